// Round 1
// baseline (75.942 us; speedup 1.0000x reference)
//
#include <hip/hip_runtime.h>

#define NN 256
#define AA 1024
#define BB 128
#define CC 32
#define JJ (BB * CC)      // 4096
#define OUTW (AA + BB)    // 1152

// ---------------------------------------------------------------------------
// Kernel 1: M[n][j] = sum_a x[n][a] * W[a][j],  W = T viewed as (1024, 4096)
// 64x64 output tile per block, K-chunk 32, 4x4 accumulators per thread.
// Grid (JJ/64=64, NN/64=4) = 256 blocks of 256 threads -> 1 block/CU.
// ---------------------------------------------------------------------------
__global__ __launch_bounds__(256) void gemm_m(const float* __restrict__ x,
                                              const float* __restrict__ W,
                                              float* __restrict__ M) {
    __shared__ float xs[32][68];   // [k][row], padded (68 = 4*17, keeps 16B align)
    __shared__ float ws[32][68];   // [k][col]

    const int tid = threadIdx.x;
    const int tx = tid & 15;       // col group
    const int ty = tid >> 4;       // row group
    const int row0 = blockIdx.y * 64;
    const int col0 = blockIdx.x * 64;

    float acc[4][4];
#pragma unroll
    for (int i = 0; i < 4; ++i)
#pragma unroll
        for (int j = 0; j < 4; ++j) acc[i][j] = 0.f;

    for (int k0 = 0; k0 < AA; k0 += 32) {
        // stage x chunk: 64 rows x 32 k, transposed into xs[k][r]
#pragma unroll
        for (int p = 0; p < 2; ++p) {
            int t = tid + p * 256;          // 0..511
            int r = t >> 3;                 // 0..63
            int kq = (t & 7) * 4;           // 0..28
            float4 v = *(const float4*)&x[(size_t)(row0 + r) * AA + k0 + kq];
            xs[kq + 0][r] = v.x;
            xs[kq + 1][r] = v.y;
            xs[kq + 2][r] = v.z;
            xs[kq + 3][r] = v.w;
        }
        // stage W chunk: 32 k x 64 cols
#pragma unroll
        for (int p = 0; p < 2; ++p) {
            int t = tid + p * 256;          // 0..511
            int k = t >> 4;                 // 0..31
            int cq = (t & 15) * 4;          // 0..60
            *(float4*)&ws[k][cq] =
                *(const float4*)&W[(size_t)(k0 + k) * JJ + col0 + cq];
        }
        __syncthreads();

#pragma unroll
        for (int k = 0; k < 32; ++k) {
            float a[4], b[4];
            *(float4*)a = *(const float4*)&xs[k][ty * 4];
            *(float4*)b = *(const float4*)&ws[k][tx * 4];
#pragma unroll
            for (int i = 0; i < 4; ++i)
#pragma unroll
                for (int j = 0; j < 4; ++j) acc[i][j] = fmaf(a[i], b[j], acc[i][j]);
        }
        __syncthreads();
    }

#pragma unroll
    for (int i = 0; i < 4; ++i) {
        float4 v;
        v.x = acc[i][0]; v.y = acc[i][1]; v.z = acc[i][2]; v.w = acc[i][3];
        *(float4*)&M[(size_t)(row0 + ty * 4 + i) * JJ + col0 + tx * 4] = v;
    }
}

// ---------------------------------------------------------------------------
// Kernel 2: o[n][b] = sum_m exp(-sum_c |M[n][b*32+c] - M[m][b*32+c]|)
// Grid (128 b, 2 n-half). Block: 256 threads = 128 n x 2 m-halves.
// M[:,b,:] (32 KB) staged in LDS; inner reads are wave-uniform broadcasts.
// ---------------------------------------------------------------------------
__global__ __launch_bounds__(256) void pairwise_o(const float* __restrict__ M,
                                                  float* __restrict__ out) {
    __shared__ float Mb[256][32];
    __shared__ float red[128];

    const int b = blockIdx.x;       // 0..127
    const int nh = blockIdx.y;      // 0..1
    const int tid = threadIdx.x;

    // stage M[m][b*32 + c] for all m: 2048 float4s, 256 threads -> 8 each
#pragma unroll
    for (int p = 0; p < 8; ++p) {
        int t = tid + p * 256;      // 0..2047
        int m = t >> 3;
        int cq = (t & 7) * 4;
        *(float4*)&Mb[m][cq] = *(const float4*)&M[(size_t)m * JJ + b * CC + cq];
    }

    const int nl = tid & 127;
    const int half = tid >> 7;
    const int n = nh * 128 + nl;

    // own row from global (L2-resident; avoids 16-way LDS conflict)
    float mine[32];
#pragma unroll
    for (int c = 0; c < 32; c += 4) {
        float4 v = *(const float4*)&M[(size_t)n * JJ + b * CC + c];
        mine[c + 0] = v.x; mine[c + 1] = v.y; mine[c + 2] = v.z; mine[c + 3] = v.w;
    }

    __syncthreads();

    float o = 0.f;
    const int m0 = half * 128;
    for (int m = m0; m < m0 + 128; ++m) {
        float l1 = 0.f;
#pragma unroll
        for (int c = 0; c < 32; ++c) l1 += fabsf(mine[c] - Mb[m][c]);
        o += __expf(-l1);
    }

    if (half) red[nl] = o;
    __syncthreads();
    if (!half) {
        o += red[nl];
        out[(size_t)n * OUTW + AA + b] = o;
    }
}

// ---------------------------------------------------------------------------
// Kernel 3: out[n][0:1024] = x[n][:]
// ---------------------------------------------------------------------------
__global__ __launch_bounds__(256) void copy_x(const float* __restrict__ x,
                                              float* __restrict__ out) {
    const int n = blockIdx.x;
    const int t = threadIdx.x;
    *(float4*)&out[(size_t)n * OUTW + t * 4] =
        *(const float4*)&x[(size_t)n * AA + t * 4];
}

extern "C" void kernel_launch(void* const* d_in, const int* in_sizes, int n_in,
                              void* d_out, int out_size, void* d_ws, size_t ws_size,
                              hipStream_t stream) {
    const float* x = (const float*)d_in[0];
    const float* T = (const float*)d_in[1];   // (1024, 128, 32) == (1024, 4096)
    float* out = (float*)d_out;
    float* M = (float*)d_ws;                  // needs 256*4096*4 = 4 MB

    dim3 gGemm(JJ / 64, NN / 64);             // (64, 4)
    gemm_m<<<gGemm, 256, 0, stream>>>(x, T, M);

    copy_x<<<NN, 256, 0, stream>>>(x, out);

    dim3 gPair(BB, 2);                        // (128, 2)
    pairwise_o<<<gPair, 256, 0, stream>>>(M, out);
}

// Round 2
// 42.782 us; speedup vs baseline: 1.7751x; 1.7751x over previous
//
#include <hip/hip_runtime.h>
#include <hip/hip_fp16.h>
#include <hip/hip_bf16.h>

#define NN 256
#define AA 1024
#define BB 128
#define CC 32
#define JJ 4096          // B*C
#define OUTW 1152        // A + B

typedef __attribute__((ext_vector_type(8))) short short8v;
typedef __attribute__((ext_vector_type(4))) float floatx4;

__device__ __forceinline__ unsigned short f2bf(float f) {
    __hip_bfloat16 h = __float2bfloat16(f);   // RNE hardware convert
    return *(unsigned short*)&h;
}

// ---------------------------------------------------------------------------
// convT: T f32 [1024 k][4096 j] -> Tt bf16 [4096 j][1024 k] (transposed so
// both MFMA fragments can read 8 consecutive k per lane). 64x64 tiles via LDS.
// ---------------------------------------------------------------------------
__global__ __launch_bounds__(256) void convT(const float* __restrict__ T,
                                             unsigned short* __restrict__ Tt) {
    __shared__ float ts[64][68];     // [k][j], pad 68 keeps float4 writes 16B-aligned
    const int t = threadIdx.x;
    const int c0 = blockIdx.x * 64;  // j
    const int k0 = blockIdx.y * 64;  // k
#pragma unroll
    for (int p = 0; p < 4; ++p) {
        int r = p * 16 + (t >> 4);
        int c4 = (t & 15) * 4;
        *(float4*)&ts[r][c4] = *(const float4*)&T[(size_t)(k0 + r) * JJ + c0 + c4];
    }
    __syncthreads();
#pragma unroll
    for (int p = 0; p < 2; ++p) {
        int oc = p * 32 + (t >> 3);
        int ok = (t & 7) * 8;
        unsigned short h[8];
#pragma unroll
        for (int j = 0; j < 8; ++j) h[j] = f2bf(ts[ok + j][oc]);
        uint4 pk;
        pk.x = (unsigned)h[0] | ((unsigned)h[1] << 16);
        pk.y = (unsigned)h[2] | ((unsigned)h[3] << 16);
        pk.z = (unsigned)h[4] | ((unsigned)h[5] << 16);
        pk.w = (unsigned)h[6] | ((unsigned)h[7] << 16);
        *(uint4*)&Tt[(size_t)(c0 + oc) * AA + k0 + ok] = pk;
    }
}

// ---------------------------------------------------------------------------
// gemm_mfma: M[n][j] = sum_k x[n][k] * T[k][j], bf16 MFMA 16x16x32, f32 acc.
// Tile 32 rows x 64 cols, TK=64. Grid (4096/64=64, 256/32=8) = 512 blocks
// (2/CU, 8 waves/CU). Wave w -> cols [w*16, w*16+16), 2 row-tiles each.
// LDS rows padded 64->72 elems: fragment b128 reads land 8 lanes per bank-quad
// (uniform) -> conflict-free. Output M stored as f16.
// ---------------------------------------------------------------------------
__global__ __launch_bounds__(256) void gemm_mfma(const float* __restrict__ x,
                                                 const unsigned short* __restrict__ Tt,
                                                 __half* __restrict__ Mh) {
    __shared__ unsigned short Ash[32][72];   // [row][k]
    __shared__ unsigned short Bsh[64][72];   // [col][k]
    const int tid = threadIdx.x;
    const int lane = tid & 63;
    const int w = tid >> 6;
    const int col0 = blockIdx.x * 64;
    const int row0 = blockIdx.y * 32;

    floatx4 acc0 = {0.f, 0.f, 0.f, 0.f};
    floatx4 acc1 = {0.f, 0.f, 0.f, 0.f};

    const int ar = tid >> 3;         // A stage: row 0..31
    const int ak = (tid & 7) * 8;    //          k offset (8 f32 -> 8 bf16)
    const int bc = tid >> 2;         // B stage: col 0..63
    const int bk = (tid & 3) * 16;   //          k offset (16 bf16)

    const float* xrow = &x[(size_t)(row0 + ar) * AA + ak];
    const unsigned short* trow = &Tt[(size_t)(col0 + bc) * AA + bk];

    for (int k0 = 0; k0 < AA; k0 += 64) {
        float4 va = *(const float4*)&xrow[k0];
        float4 vb = *(const float4*)&xrow[k0 + 4];
        uint4 pa;
        pa.x = (unsigned)f2bf(va.x) | ((unsigned)f2bf(va.y) << 16);
        pa.y = (unsigned)f2bf(va.z) | ((unsigned)f2bf(va.w) << 16);
        pa.z = (unsigned)f2bf(vb.x) | ((unsigned)f2bf(vb.y) << 16);
        pa.w = (unsigned)f2bf(vb.z) | ((unsigned)f2bf(vb.w) << 16);
        *(uint4*)&Ash[ar][ak] = pa;
        uint4 q0 = *(const uint4*)&trow[k0];
        uint4 q1 = *(const uint4*)&trow[k0 + 8];
        *(uint4*)&Bsh[bc][bk] = q0;
        *(uint4*)&Bsh[bc][bk + 8] = q1;
        __syncthreads();

        const int g = lane >> 4;
        const int rf = lane & 15;
#pragma unroll
        for (int ks = 0; ks < 2; ++ks) {
            const int kb = ks * 32 + g * 8;
            short8v bfrag = *(const short8v*)&Bsh[w * 16 + rf][kb];
            short8v a0 = *(const short8v*)&Ash[rf][kb];
            short8v a1 = *(const short8v*)&Ash[16 + rf][kb];
            acc0 = __builtin_amdgcn_mfma_f32_16x16x32_bf16(a0, bfrag, acc0, 0, 0, 0);
            acc1 = __builtin_amdgcn_mfma_f32_16x16x32_bf16(a1, bfrag, acc1, 0, 0, 0);
        }
        __syncthreads();
    }

    // C/D layout: col = lane&15, row = (lane>>4)*4 + reg   [m89-verified]
    const int colw = col0 + w * 16 + (lane & 15);
    const int rbase = row0 + (lane >> 4) * 4;
#pragma unroll
    for (int r = 0; r < 4; ++r) {
        Mh[(size_t)(rbase + r) * JJ + colw] = __float2half(acc0[r]);
        Mh[(size_t)(rbase + 16 + r) * JJ + colw] = __float2half(acc1[r]);
    }
}

// ---------------------------------------------------------------------------
// pairwise_h: o[n][b] = sum_m exp(-sum_c |M[n][b,c] - M[m][b,c]|), f16 packed.
// Grid (128 b, 2 n-half), 512 threads = 128 n x 4 m-quarters (2 waves/SIMD).
// Mb rows read wave-uniform (m is loop index) -> broadcast, conflict-free.
// Self term m==n gives exactly exp(0)=1; off-diagonal ~e^-40 -> f16 accum safe.
// ---------------------------------------------------------------------------
__global__ __launch_bounds__(512) void pairwise_h(const __half* __restrict__ Mh,
                                                  float* __restrict__ out) {
    __shared__ __half Mb[256][32];
    __shared__ float red[3][128];
    const int b = blockIdx.x;
    const int nh = blockIdx.y;
    const int tid = threadIdx.x;

    {   // stage all 256 rows of M[:, b, :] (16 KB)
        int m = tid >> 1;
        int ch = (tid & 1) * 16;
        uint4 v0 = *(const uint4*)&Mh[(size_t)m * JJ + b * CC + ch];
        uint4 v1 = *(const uint4*)&Mh[(size_t)m * JJ + b * CC + ch + 8];
        *(uint4*)&Mb[m][ch] = v0;
        *(uint4*)&Mb[m][ch + 8] = v1;
    }

    const int nl = tid & 127;
    const int mq = tid >> 7;
    const int n = nh * 128 + nl;

    union { uint4 u; __half2 h[4]; } mv[4];
#pragma unroll
    for (int i = 0; i < 4; ++i)
        mv[i].u = *(const uint4*)&Mh[(size_t)n * JJ + b * CC + i * 8];

    __syncthreads();

    float o = 0.f;
    const int m0 = mq * 64;
    for (int m = m0; m < m0 + 64; ++m) {
        union { uint4 u; __half2 h[4]; } rv[4];
#pragma unroll
        for (int i = 0; i < 4; ++i)
            rv[i].u = *(const uint4*)&Mb[m][i * 8];
        __half2 a0 = __habs2(__hsub2(mv[0].h[0], rv[0].h[0]));
        __half2 a1 = __habs2(__hsub2(mv[0].h[1], rv[0].h[1]));
        __half2 a2 = __habs2(__hsub2(mv[0].h[2], rv[0].h[2]));
        __half2 a3 = __habs2(__hsub2(mv[0].h[3], rv[0].h[3]));
#pragma unroll
        for (int i = 1; i < 4; ++i) {
            a0 = __hadd2(a0, __habs2(__hsub2(mv[i].h[0], rv[i].h[0])));
            a1 = __hadd2(a1, __habs2(__hsub2(mv[i].h[1], rv[i].h[1])));
            a2 = __hadd2(a2, __habs2(__hsub2(mv[i].h[2], rv[i].h[2])));
            a3 = __hadd2(a3, __habs2(__hsub2(mv[i].h[3], rv[i].h[3])));
        }
        __half2 s = __hadd2(__hadd2(a0, a1), __hadd2(a2, a3));
        float2 lf = __half22float2(s);
        o += __expf(-(lf.x + lf.y));
    }

    if (mq) red[mq - 1][nl] = o;
    __syncthreads();
    if (mq == 0) {
        o += red[0][nl] + red[1][nl] + red[2][nl];
        out[(size_t)n * OUTW + AA + b] = o;
    }
}

// ---------------------------------------------------------------------------
__global__ __launch_bounds__(256) void copy_x(const float* __restrict__ x,
                                              float* __restrict__ out) {
    const int n = blockIdx.x;
    const int t = threadIdx.x;
    *(float4*)&out[(size_t)n * OUTW + t * 4] =
        *(const float4*)&x[(size_t)n * AA + t * 4];
}

// ======================= fallback f32 path (ws < 10 MB) =====================
__global__ __launch_bounds__(256) void gemm_m(const float* __restrict__ x,
                                              const float* __restrict__ W,
                                              float* __restrict__ M) {
    __shared__ float xs[32][68];
    __shared__ float ws2[32][68];
    const int tid = threadIdx.x;
    const int tx = tid & 15, ty = tid >> 4;
    const int row0 = blockIdx.y * 64, col0 = blockIdx.x * 64;
    float acc[4][4];
#pragma unroll
    for (int i = 0; i < 4; ++i)
#pragma unroll
        for (int j = 0; j < 4; ++j) acc[i][j] = 0.f;
    for (int k0 = 0; k0 < AA; k0 += 32) {
#pragma unroll
        for (int p = 0; p < 2; ++p) {
            int t = tid + p * 256;
            int r = t >> 3, kq = (t & 7) * 4;
            float4 v = *(const float4*)&x[(size_t)(row0 + r) * AA + k0 + kq];
            xs[kq][r] = v.x; xs[kq + 1][r] = v.y; xs[kq + 2][r] = v.z; xs[kq + 3][r] = v.w;
        }
#pragma unroll
        for (int p = 0; p < 2; ++p) {
            int t = tid + p * 256;
            int k = t >> 4, cq = (t & 15) * 4;
            *(float4*)&ws2[k][cq] = *(const float4*)&W[(size_t)(k0 + k) * JJ + col0 + cq];
        }
        __syncthreads();
#pragma unroll
        for (int k = 0; k < 32; ++k) {
            float a[4], bb[4];
            *(float4*)a = *(const float4*)&xs[k][ty * 4];
            *(float4*)bb = *(const float4*)&ws2[k][tx * 4];
#pragma unroll
            for (int i = 0; i < 4; ++i)
#pragma unroll
                for (int j = 0; j < 4; ++j) acc[i][j] = fmaf(a[i], bb[j], acc[i][j]);
        }
        __syncthreads();
    }
#pragma unroll
    for (int i = 0; i < 4; ++i) {
        float4 v; v.x = acc[i][0]; v.y = acc[i][1]; v.z = acc[i][2]; v.w = acc[i][3];
        *(float4*)&M[(size_t)(row0 + ty * 4 + i) * JJ + col0 + tx * 4] = v;
    }
}

__global__ __launch_bounds__(256) void pairwise_o(const float* __restrict__ M,
                                                  float* __restrict__ out) {
    __shared__ float Mb[256][32];
    __shared__ float red[128];
    const int b = blockIdx.x, nh = blockIdx.y, tid = threadIdx.x;
#pragma unroll
    for (int p = 0; p < 8; ++p) {
        int t = tid + p * 256;
        int m = t >> 3, cq = (t & 7) * 4;
        *(float4*)&Mb[m][cq] = *(const float4*)&M[(size_t)m * JJ + b * CC + cq];
    }
    const int nl = tid & 127, half = tid >> 7;
    const int n = nh * 128 + nl;
    float mine[32];
#pragma unroll
    for (int c = 0; c < 32; c += 4) {
        float4 v = *(const float4*)&M[(size_t)n * JJ + b * CC + c];
        mine[c] = v.x; mine[c + 1] = v.y; mine[c + 2] = v.z; mine[c + 3] = v.w;
    }
    __syncthreads();
    float o = 0.f;
    const int m0 = half * 128;
    for (int m = m0; m < m0 + 128; ++m) {
        float l1 = 0.f;
#pragma unroll
        for (int c = 0; c < 32; ++c) l1 += fabsf(mine[c] - Mb[m][c]);
        o += __expf(-l1);
    }
    if (half) red[nl] = o;
    __syncthreads();
    if (!half) { o += red[nl]; out[(size_t)n * OUTW + AA + b] = o; }
}

// ===========================================================================
extern "C" void kernel_launch(void* const* d_in, const int* in_sizes, int n_in,
                              void* d_out, int out_size, void* d_ws, size_t ws_size,
                              hipStream_t stream) {
    const float* x = (const float*)d_in[0];
    const float* T = (const float*)d_in[1];
    float* out = (float*)d_out;

    const size_t ttBytes = (size_t)JJ * AA * sizeof(unsigned short);  // 8 MB
    const size_t mhBytes = (size_t)NN * JJ * sizeof(__half);          // 2 MB

    if (ws_size >= ttBytes + mhBytes) {
        unsigned short* Tt = (unsigned short*)d_ws;
        __half* Mh = (__half*)((char*)d_ws + ttBytes);
        convT<<<dim3(64, 16), 256, 0, stream>>>(T, Tt);
        copy_x<<<NN, 256, 0, stream>>>(x, out);
        gemm_mfma<<<dim3(64, 8), 256, 0, stream>>>(x, Tt, Mh);
        pairwise_h<<<dim3(BB, 2), 512, 0, stream>>>(Mh, out);
    } else {
        float* M = (float*)d_ws;  // 4 MB
        gemm_m<<<dim3(JJ / 64, NN / 64), 256, 0, stream>>>(x, T, M);
        copy_x<<<NN, 256, 0, stream>>>(x, out);
        pairwise_o<<<dim3(BB, 2), 256, 0, stream>>>(M, out);
    }
}

// Round 4
// 36.758 us; speedup vs baseline: 2.0660x; 1.1639x over previous
//
#include <hip/hip_runtime.h>
#include <hip/hip_fp16.h>
#include <hip/hip_bf16.h>

#define NN 256
#define AA 1024
#define BB 128
#define CC 32
#define JJ 4096          // B*C
#define OUTW 1152        // A + B

typedef __attribute__((ext_vector_type(8))) short short8v;
typedef __attribute__((ext_vector_type(4))) float floatx4;

__device__ __forceinline__ unsigned short f2bf(float f) {
    __hip_bfloat16 h = __float2bfloat16(f);   // RNE hardware convert
    return *(unsigned short*)&h;
}

// ---------------------------------------------------------------------------
// gemm_fused: M[n][j] = sum_k x[n][k] * T[k][j]; f32 inputs, bf16 MFMA
// 16x16x32, f32 acc, f16 output M.
// Tile 64n x 64j, TK=64, 512 threads (8 waves), grid (64 j, 4 n) = 256 blocks.
// Wave w: rows (w&3)*16..+16, cols (w>>2)*32..+32 (2 col tiles) -> per k-step
// 6 ds_read_b128 + 4 MFMA.
// LDS: both tiles [row][64k] bf16 (128B row stride). Swizzle (T2, rule 21):
//   stored_byte(row, kbyte) = row*128 + (kbyte ^ ((row&7)<<4))
// applied identically on write AND read; kbyte and swz both live in bits 4-6
// so the result stays inside the row -> always in-bounds.
// B is transposed on stage: 4 k-strided float2 loads (j-coalesced) per thread.
// ---------------------------------------------------------------------------
__global__ __launch_bounds__(512) void gemm_fused(const float* __restrict__ x,
                                                  const float* __restrict__ T,
                                                  __half* __restrict__ Mh) {
    __shared__ unsigned short Ash[64 * 64];   // swizzled [n-row][k], 8 KB
    __shared__ unsigned short Bsh[64 * 64];   // swizzled [j-col][k], 8 KB

    const int tid = threadIdx.x;
    const int lane = tid & 63;
    const int w = tid >> 6;                   // 0..7
    const int col0 = blockIdx.x * 64;
    const int row0 = blockIdx.y * 64;

    // staging assignments
    const int ar = tid >> 3;                  // A row 0..63
    const int ak = (tid & 7) * 8;             // A k elem offset (bytes = *2)
    const int bj = (tid & 31) * 2;            // B col pair 0..62
    const int bk = (tid >> 5) * 4;            // B k elem offset 0..60

    // compute assignments
    const int g = lane >> 4;                  // k-group 0..3
    const int rf = lane & 15;
    const int arow = (w & 3) * 16 + rf;       // fragment A row
    const int bcol = (w >> 2) * 32 + rf;      // fragment B col (first tile)

    floatx4 acc0 = {0.f, 0.f, 0.f, 0.f};
    floatx4 acc1 = {0.f, 0.f, 0.f, 0.f};

    const float* xrow = &x[(size_t)(row0 + ar) * AA + ak];
    const float* tcol = &T[(size_t)bk * JJ + col0 + bj];

    // write offsets: row*128 + (kbyte ^ swz(row))
    const int aWr = ar * 128 + ((ak * 2) ^ ((ar & 7) << 4));
    const int bWr0 = bj * 128 + ((bk * 2) ^ ((bj & 7) << 4));
    const int bWr1 = (bj + 1) * 128 + ((bk * 2) ^ (((bj + 1) & 7) << 4));

    // read offsets, one per ks in {0,1}: kbyte = ks*64 + g*16
    const int swzA = (arow & 7) << 4;
    const int swzB = (bcol & 7) << 4;         // (bcol+16)&7 == bcol&7
    const int aRd0 = arow * 128 + ((g * 16) ^ swzA);
    const int aRd1 = arow * 128 + ((64 + g * 16) ^ swzA);
    const int bBase0 = bcol * 128;
    const int bBase1 = (bcol + 16) * 128;
    const int kOffB0 = (g * 16) ^ swzB;
    const int kOffB1 = (64 + g * 16) ^ swzB;

    for (int k0 = 0; k0 < AA; k0 += 64) {
        // ---- stage A: 1 row x 8 k per thread ----
        float4 va = *(const float4*)&xrow[k0];
        float4 vb = *(const float4*)&xrow[k0 + 4];
        uint4 pa;
        pa.x = (unsigned)f2bf(va.x) | ((unsigned)f2bf(va.y) << 16);
        pa.y = (unsigned)f2bf(va.z) | ((unsigned)f2bf(va.w) << 16);
        pa.z = (unsigned)f2bf(vb.x) | ((unsigned)f2bf(vb.y) << 16);
        pa.w = (unsigned)f2bf(vb.z) | ((unsigned)f2bf(vb.w) << 16);
        *(uint4*)((char*)Ash + aWr) = pa;

        // ---- stage B (transpose): 2 j x 4 k per thread ----
        const float* tb = &tcol[(size_t)k0 * JJ];
        float2 t0 = *(const float2*)&tb[0];
        float2 t1 = *(const float2*)&tb[JJ];
        float2 t2 = *(const float2*)&tb[2 * JJ];
        float2 t3 = *(const float2*)&tb[3 * JJ];
        uint2 p0, p1;
        p0.x = (unsigned)f2bf(t0.x) | ((unsigned)f2bf(t1.x) << 16);
        p0.y = (unsigned)f2bf(t2.x) | ((unsigned)f2bf(t3.x) << 16);
        p1.x = (unsigned)f2bf(t0.y) | ((unsigned)f2bf(t1.y) << 16);
        p1.y = (unsigned)f2bf(t2.y) | ((unsigned)f2bf(t3.y) << 16);
        *(uint2*)((char*)Bsh + bWr0) = p0;
        *(uint2*)((char*)Bsh + bWr1) = p1;

        __syncthreads();

        {
            short8v a0 = *(const short8v*)((char*)Ash + aRd0);
            short8v b00 = *(const short8v*)((char*)Bsh + bBase0 + kOffB0);
            short8v b10 = *(const short8v*)((char*)Bsh + bBase1 + kOffB0);
            acc0 = __builtin_amdgcn_mfma_f32_16x16x32_bf16(a0, b00, acc0, 0, 0, 0);
            acc1 = __builtin_amdgcn_mfma_f32_16x16x32_bf16(a0, b10, acc1, 0, 0, 0);
            short8v a1 = *(const short8v*)((char*)Ash + aRd1);
            short8v b01 = *(const short8v*)((char*)Bsh + bBase0 + kOffB1);
            short8v b11 = *(const short8v*)((char*)Bsh + bBase1 + kOffB1);
            acc0 = __builtin_amdgcn_mfma_f32_16x16x32_bf16(a1, b01, acc0, 0, 0, 0);
            acc1 = __builtin_amdgcn_mfma_f32_16x16x32_bf16(a1, b11, acc1, 0, 0, 0);
        }
        __syncthreads();
    }

    // C/D layout: col = lane&15, row = (lane>>4)*4 + reg
    const int colw = col0 + (w >> 2) * 32 + rf;
    const int rbase = row0 + (w & 3) * 16 + (lane >> 4) * 4;
#pragma unroll
    for (int r = 0; r < 4; ++r) {
        Mh[(size_t)(rbase + r) * JJ + colw] = __float2half(acc0[r]);
        Mh[(size_t)(rbase + r) * JJ + colw + 16] = __float2half(acc1[r]);
    }
}

// ---------------------------------------------------------------------------
// pairwise_h: o[n][b] = sum_m exp(-sum_c |M[n][b,c] - M[m][b,c]|), f16 packed.
// Grid (128 b, 2 n-half), 512 threads = 128 n x 4 m-quarters.
// ---------------------------------------------------------------------------
__global__ __launch_bounds__(512) void pairwise_h(const __half* __restrict__ Mh,
                                                  float* __restrict__ out) {
    __shared__ __half Mb[256][32];
    __shared__ float red[3][128];
    const int b = blockIdx.x;
    const int nh = blockIdx.y;
    const int tid = threadIdx.x;

    {   // stage all 256 rows of M[:, b, :] (16 KB)
        int m = tid >> 1;
        int ch = (tid & 1) * 16;
        uint4 v0 = *(const uint4*)&Mh[(size_t)m * JJ + b * CC + ch];
        uint4 v1 = *(const uint4*)&Mh[(size_t)m * JJ + b * CC + ch + 8];
        *(uint4*)&Mb[m][ch] = v0;
        *(uint4*)&Mb[m][ch + 8] = v1;
    }

    const int nl = tid & 127;
    const int mq = tid >> 7;
    const int n = nh * 128 + nl;

    union { uint4 u; __half2 h[4]; } mv[4];
#pragma unroll
    for (int i = 0; i < 4; ++i)
        mv[i].u = *(const uint4*)&Mh[(size_t)n * JJ + b * CC + i * 8];

    __syncthreads();

    float o = 0.f;
    const int m0 = mq * 64;
    for (int m = m0; m < m0 + 64; ++m) {
        union { uint4 u; __half2 h[4]; } rv[4];
#pragma unroll
        for (int i = 0; i < 4; ++i)
            rv[i].u = *(const uint4*)&Mb[m][i * 8];
        __half2 a0 = __habs2(__hsub2(mv[0].h[0], rv[0].h[0]));
        __half2 a1 = __habs2(__hsub2(mv[0].h[1], rv[0].h[1]));
        __half2 a2 = __habs2(__hsub2(mv[0].h[2], rv[0].h[2]));
        __half2 a3 = __habs2(__hsub2(mv[0].h[3], rv[0].h[3]));
#pragma unroll
        for (int i = 1; i < 4; ++i) {
            a0 = __hadd2(a0, __habs2(__hsub2(mv[i].h[0], rv[i].h[0])));
            a1 = __hadd2(a1, __habs2(__hsub2(mv[i].h[1], rv[i].h[1])));
            a2 = __hadd2(a2, __habs2(__hsub2(mv[i].h[2], rv[i].h[2])));
            a3 = __hadd2(a3, __habs2(__hsub2(mv[i].h[3], rv[i].h[3])));
        }
        __half2 s = __hadd2(__hadd2(a0, a1), __hadd2(a2, a3));
        float2 lf = __half22float2(s);
        o += __expf(-(lf.x + lf.y));
    }

    if (mq) red[mq - 1][nl] = o;
    __syncthreads();
    if (mq == 0) {
        o += red[0][nl] + red[1][nl] + red[2][nl];
        out[(size_t)n * OUTW + AA + b] = o;
    }
}

// ---------------------------------------------------------------------------
__global__ __launch_bounds__(256) void copy_x(const float* __restrict__ x,
                                              float* __restrict__ out) {
    const int n = blockIdx.x;
    const int t = threadIdx.x;
    *(float4*)&out[(size_t)n * OUTW + t * 4] =
        *(const float4*)&x[(size_t)n * AA + t * 4];
}

// ===========================================================================
extern "C" void kernel_launch(void* const* d_in, const int* in_sizes, int n_in,
                              void* d_out, int out_size, void* d_ws, size_t ws_size,
                              hipStream_t stream) {
    const float* x = (const float*)d_in[0];
    const float* T = (const float*)d_in[1];
    float* out = (float*)d_out;
    __half* Mh = (__half*)d_ws;               // needs 256*4096*2 = 2 MB

    gemm_fused<<<dim3(64, 4), 512, 0, stream>>>(x, T, Mh);
    copy_x<<<NN, 256, 0, stream>>>(x, out);
    pairwise_h<<<dim3(BB, 2), 512, 0, stream>>>(Mh, out);
}